// Round 16
// baseline (1700.139 us; speedup 1.0000x reference)
//
#include <hip/hip_runtime.h>

typedef _Float16 f16;
typedef _Float16 f16x8 __attribute__((ext_vector_type(8)));
typedef _Float16 f16x4 __attribute__((ext_vector_type(4)));
typedef float    f32x4 __attribute__((ext_vector_type(4)));
typedef float    f32x16 __attribute__((ext_vector_type(16)));
typedef unsigned long long u64;

#define N_   8
#define C_   256
#define H_   128
#define W_   128
#define K_   9
#define PAD_ 4
#define WP_  136                    // padded w rows: wp = w + 4, rows 0..135, pads zeroed

#define WELEMS (8*9*16*64*8)        // 589824 = C_*C_*K_ fragment-linear (32x32 layout)
#define XT_SZ  (N_*WP_*256)
#define XBUF_F16 (N_*WP_*512)       // one X buffer: per row 256 hi | 256 lo f16 (pre-swizzled)
#define NBLK   256
#define NSTEP  253
// LDS: X tile 40K | red 32K | wcnt. Request 84992 (>80KB) -> 1 block/CU guaranteed;
// with 1024-thread blocks the natural occupancy (4 waves/EU) == compiler's default
// target, so the 128-VGPR budget is real and the ~111-VGPR working set fits.
#define RED_OFF  40960
#define WCNT_OFF 73728
#define LDS_BYTES 84992

// granule (8 ci = 16B) rotated by 5*wp within 32-granule row (odd mult -> conflict-free b128)
__device__ __host__ inline int xpos(int ci, int wp) {
    int g = ((ci >> 3) + 5 * wp) & 31;
    return g * 8 + (ci & 7);
}

// ---------------- weight prep ----------------
__global__ __launch_bounds__(256) void prep_w(const float* __restrict__ w,
                                              f16* __restrict__ wh, f16* __restrict__ wl) {
    int t = blockIdx.x * 256 + threadIdx.x;
    if (t >= WELEMS) return;
    int j = t & 7;      int q = t >> 3;
    int lane = q & 63;  q >>= 6;
    int c = q & 15;     q >>= 4;
    int k = q % 9;      int ct = q / 9;
    int co = ct * 32 + (lane & 31);
    int ci = c * 16 + (lane >> 5) * 8 + j;
    float wf = w[(co * C_ + ci) * K_ + k];
    f16 hi = (f16)wf;
    f16 lo = (f16)(wf - (float)hi);
    wh[t] = hi;  wl[t] = lo;
}

// ---------------- X init ----------------
__global__ __launch_bounds__(256) void prep_x0(const float* __restrict__ fea,
                                               f16* __restrict__ xb0, f16* __restrict__ xb1) {
    int t = blockIdx.x * 256 + threadIdx.x;
    if (t >= XT_SZ) return;
    int ci = t & 255;
    int wp = (t >> 8) % WP_;
    int n  = t / (WP_ * 256);
    int w  = wp - PAD_;
    bool pad = (unsigned)w >= (unsigned)W_;
    float v = pad ? 0.0f : fea[((size_t)(n * C_ + ci) * H_ + 0) * W_ + w];
    f16 hi = (f16)v;
    f16 lo = (f16)(v - (float)hi);
    size_t row = ((size_t)n * WP_ + wp) * 512;
    int p = xpos(ci, wp);
    xb0[row + p] = hi;  xb0[row + 256 + p] = lo;
    if (pad) { xb1[row + p] = (f16)0.f; xb1[row + 256 + p] = (f16)0.f; }
}

// ---------------- out row0 = fea row0 ----------------
__global__ __launch_bounds__(256) void copy_row0(const float* __restrict__ fea,
                                                 float* __restrict__ out) {
    int idx = blockIdx.x * 256 + threadIdx.x;
    if (idx >= N_ * C_ * W_) return;
    int w = idx % W_;
    int nc = idx / W_;
    size_t off = (size_t)nc * (H_ * W_) + w;
    out[off] = fea[off];
}

// non-rematerializable definition: keeps fragments as asm-defined values
#define TIE(x) asm volatile("" : "+v"(x))

// ---------------- persistent scan kernel (32x32x16 MFMA, 16 waves x 16-ci chunks) ----------------
// 256 blocks x 1024 threads = 1 block/CU (LDS-forced), 4 waves/SIMD.
// Block b: n=b&7, ct=(b>>3)&7 (32 co), wq=b>>6 (32 w). Wave wv owns ci-chunk16 wv:
// weights = 18 frags = 72 VGPR, one merged f32x16 acc -> total ~111 VGPR, fits 128 budget.
// Reduction: waves 8-15 write partials -> waves 0-7 combine -> duty reduce 8 slots.
// Duty: waves 0-3 out-stores || waves 4-7 X-stores+flag; wave 8 polls (overlaps epilogue).
__global__ __launch_bounds__(1024, 4)
void conv_persist(
    f16* __restrict__ xb0, f16* __restrict__ xb1,
    const f16* __restrict__ whp, const f16* __restrict__ wlp,
    const float* __restrict__ bias, const float* __restrict__ fea,
    float* out, unsigned* ctr)
{
    extern __shared__ unsigned char Xs[];            // [0,40960) X tile (40 rows x 1024B hi|lo)
    f32x4*    red  = (f32x4*)(Xs + RED_OFF);         // 8 slots x 4 rq x 64 lanes x 16B = 32KB
    unsigned* wcnt = (unsigned*)(Xs + WCNT_OFF);

    const int b   = blockIdx.x;
    const int n   = b & 7;
    const int ct  = (b >> 3) & 7;
    const int wq  = b >> 6;
    const int w0  = wq * 32;
    const int tid = threadIdx.x;
    const int wv  = tid >> 6;                        // 0..15
    const int l   = tid & 63;
    const int m   = l & 31;
    const int hh  = l >> 5;
    unsigned* flags = ctr + n * 64;
    const int bslot = b >> 3;                        // 0..31 within n-group

    if (tid == 0) *wcnt = 0;

    // ---- weights -> VGPR, once: 9 hi + 9 lo fragments (72 VGPR) ----
    f16x8 wkh[9], wkl[9];
    #pragma unroll
    for (int k = 0; k < 9; ++k) {
        size_t o = ((((size_t)ct * 9 + k) * 16 + wv) * 64 + l) * 8;
        wkh[k] = *(const f16x8*)&whp[o];
        wkl[k] = *(const f16x8*)&wlp[o];
    }
    #pragma unroll
    for (int k = 0; k < 9; ++k) { TIE(wkh[k]); TIE(wkl[k]); }
    __syncthreads();   // wcnt init visible

    const int dq = wv & 3;
    const int co_base = ct * 32 + dq * 8 + hh * 4;
    const size_t HW = (size_t)H_ * W_;
    float4 bv = *(const float4*)&bias[co_base];
    const float bvr[4] = {bv.x, bv.y, bv.z, bv.w};

    for (int step = 0; step < NSTEP; ++step) {
        const int  cur   = step & 1;
        const bool fwd   = step < 127;
        const int  h_out = fwd ? (step + 1) : (NSTEP - step);
        const float* radd = fwd ? fea : out;
        const size_t obase = (((size_t)(n * C_ + co_base)) * H_ + h_out) * W_ + w0 + m;
        f16* xcur = cur ? xb1 : xb0;
        f16* xnxt = cur ? xb0 : xb1;

        // ---- stage X tile: pure linear 40KB copy from IF$ (5 u64/thread) ----
        {
            const u64* src = (const u64*)(xcur + ((size_t)n * WP_ + w0) * 512);
            u64 v[5];
            #pragma unroll
            for (int ii = 0; ii < 5; ++ii)
                v[ii] = __hip_atomic_load(src + (size_t)(tid + ii * 1024),
                                          __ATOMIC_RELAXED, __HIP_MEMORY_SCOPE_AGENT);
            #pragma unroll
            for (int ii = 0; ii < 5; ++ii)
                *(u64*)(Xs + (size_t)(tid + ii * 1024) * 8) = v[ii];
        }
        // duty waves prefetch radd (latency hides under compute)
        float rv[4] = {0.f, 0.f, 0.f, 0.f};
        if (wv < 8) {
            #pragma unroll
            for (int c2 = 0; c2 < 4; ++c2)
                rv[c2] = radd[obase + (size_t)c2 * HW];
        }
        __syncthreads();                             // S1: X tile ready

        // ---- compute: 9k x {a += Wh*Xh; a += Wh*Xl; a += Wl*Xh} (27 MFMA, merged acc) ----
        f32x16 a{};
        #pragma unroll
        for (int k = 0; k < 9; ++k) {
            const int rl  = m + k;
            const int gsw = ((wv * 2 + hh + 5 * rl) & 31) * 16;
            const unsigned char* base = Xs + rl * 1024 + gsw;
            f16x8 bh = *(const f16x8*)base;
            f16x8 bl = *(const f16x8*)(base + 512);
            a = __builtin_amdgcn_mfma_f32_32x32x16_f16(wkh[k], bh, a, 0, 0, 0);
            a = __builtin_amdgcn_mfma_f32_32x32x16_f16(wkh[k], bl, a, 0, 0, 0);
            a = __builtin_amdgcn_mfma_f32_32x32x16_f16(wkl[k], bh, a, 0, 0, 0);
        }

        // ---- reduction round 1: waves 8-15 write partials ----
        if (wv >= 8) {
            #pragma unroll
            for (int rq = 0; rq < 4; ++rq) {
                f32x4 qv = {a[rq * 4 + 0], a[rq * 4 + 1], a[rq * 4 + 2], a[rq * 4 + 3]};
                red[((wv - 8) * 4 + rq) * 64 + l] = qv;
            }
        }
        __syncthreads();                             // S2: upper partials ready

        // ---- round 2: waves 0-7 combine own + counterpart into slot wv ----
        if (wv < 8) {
            #pragma unroll
            for (int rq = 0; rq < 4; ++rq) {
                f32x4 qv = {a[rq * 4 + 0], a[rq * 4 + 1], a[rq * 4 + 2], a[rq * 4 + 3]};
                red[(wv * 4 + rq) * 64 + l] = qv + red[(wv * 4 + rq) * 64 + l];
            }
        }
        __syncthreads();                             // S3: 8 combined slots ready

        const unsigned tgt = (unsigned)(step + 1);
        if (wv < 8) {
            // duty reduce: 8 slots for quad dq
            f32x4 s4 = red[(0 * 4 + dq) * 64 + l];
            #pragma unroll
            for (int cc = 1; cc < 8; ++cc)
                s4 += red[(cc * 4 + dq) * 64 + l];
            float y[4];
            #pragma unroll
            for (int c2 = 0; c2 < 4; ++c2)
                y[c2] = fmaxf(s4[c2] + bvr[c2], 0.0f) + rv[c2];

            if (wv < 4) {
                // out-duty: fp32 result rows
                #pragma unroll
                for (int c2 = 0; c2 < 4; ++c2)
                    out[obase + (size_t)c2 * HW] = y[c2];
            } else if (step < NSTEP - 1) {
                // X-duty: swizzled hi/lo carry, drain, wcnt, flag (wave 4 publishes)
                const int wp = w0 + m + PAD_;
                const size_t row = ((size_t)n * WP_ + wp) * 512;
                const int g   = (ct * 4 + dq + 5 * wp) & 31;
                const int pos = g * 8 + hh * 4;
                f16x4 hv, lv;
                #pragma unroll
                for (int c2 = 0; c2 < 4; ++c2) {
                    f16 hi = (f16)y[c2];
                    hv[c2] = hi;
                    lv[c2] = (f16)(y[c2] - (float)hi);
                }
                u64 uh, ul;
                __builtin_memcpy(&uh, &hv, 8);
                __builtin_memcpy(&ul, &lv, 8);
                __hip_atomic_store((u64*)&xnxt[row + pos],       uh, __ATOMIC_RELAXED, __HIP_MEMORY_SCOPE_AGENT);
                __hip_atomic_store((u64*)&xnxt[row + 256 + pos], ul, __ATOMIC_RELAXED, __HIP_MEMORY_SCOPE_AGENT);
                asm volatile("s_waitcnt vmcnt(0)" ::: "memory");   // X stores at IF$
                if (l == 0)
                    __hip_atomic_fetch_add(wcnt, 1u, __ATOMIC_RELAXED, __HIP_MEMORY_SCOPE_WORKGROUP);
                if (wv == 4 && l == 0) {
                    while (__hip_atomic_load(wcnt, __ATOMIC_RELAXED, __HIP_MEMORY_SCOPE_WORKGROUP) < 4u * tgt) {}
                    __hip_atomic_store(flags + bslot, tgt, __ATOMIC_RELAXED, __HIP_MEMORY_SCOPE_AGENT);
                }
            }
        } else if (wv == 8 && step < NSTEP - 1) {
            // poller wave (idle otherwise): overlaps the whole epilogue
            while (true) {
                unsigned v = tgt;
                if (l < 32)
                    v = __hip_atomic_load(flags + l, __ATOMIC_RELAXED, __HIP_MEMORY_SCOPE_AGENT);
                if (__all((int)(v >= tgt))) break;
            }
        }
        __syncthreads();                             // S4: release (guards Xs reuse)
    }
}

// ---------------- fallback (ws too small): fp32 per-step kernels ----------------
__global__ __launch_bounds__(256) void step_f32(
    const float* __restrict__ xprev, const float* __restrict__ radd,
    float* __restrict__ yout, const float* __restrict__ wsrc,
    const float* __restrict__ bias, int h_prev, int h_out)
{
    __shared__ float XsF[C_][40];
    const int t  = threadIdx.x;
    const int bx = blockIdx.x;
    const int n  = bx & 7;
    const int wb = (bx >> 3) & 3;
    const int cb = bx >> 5;
    const int w0 = wb * 32;
    {
        const size_t nbase = (size_t)n * C_ * (H_ * W_) + (size_t)h_prev * W_;
        for (int idx = t; idx < C_ * 40; idx += 256) {
            int ci = idx / 40;
            int j  = idx - ci * 40;
            int w  = w0 - PAD_ + j;
            float v = 0.0f;
            if ((unsigned)w < (unsigned)W_)
                v = xprev[nbase + (size_t)ci * (H_ * W_) + w];
            XsF[ci][j] = v;
        }
    }
    __syncthreads();
    const int co = cb * 32 + (t >> 3);
    const int w4 = (t & 7) * 4;
    const float* wr = wsrc + (size_t)co * (C_ * K_);
    float acc0 = 0.f, acc1 = 0.f, acc2 = 0.f, acc3 = 0.f;
    for (int ci = 0; ci < C_; ci++) {
        float wk[K_];
        #pragma unroll
        for (int k = 0; k < K_; k++) wk[k] = wr[ci * K_ + k];
        float xv[12];
        float4 a = *(const float4*)&XsF[ci][w4];
        float4 bq = *(const float4*)&XsF[ci][w4 + 4];
        float4 c = *(const float4*)&XsF[ci][w4 + 8];
        xv[0]=a.x; xv[1]=a.y; xv[2]=a.z; xv[3]=a.w;
        xv[4]=bq.x; xv[5]=bq.y; xv[6]=bq.z; xv[7]=bq.w;
        xv[8]=c.x; xv[9]=c.y; xv[10]=c.z; xv[11]=c.w;
        #pragma unroll
        for (int k = 0; k < K_; k++) {
            acc0 = fmaf(wk[k], xv[k],     acc0);
            acc1 = fmaf(wk[k], xv[k + 1], acc1);
            acc2 = fmaf(wk[k], xv[k + 2], acc2);
            acc3 = fmaf(wk[k], xv[k + 3], acc3);
        }
    }
    const float bb = bias[co];
    const size_t obase = (((size_t)n * C_ + co) * H_ + h_out) * W_ + w0 + w4;
    float4 r = *(const float4*)&radd[obase];
    float4 o;
    o.x = fmaxf(acc0 + bb, 0.f) + r.x;
    o.y = fmaxf(acc1 + bb, 0.f) + r.y;
    o.z = fmaxf(acc2 + bb, 0.f) + r.z;
    o.w = fmaxf(acc3 + bb, 0.f) + r.w;
    *(float4*)&yout[obase] = o;
}

extern "C" void kernel_launch(void* const* d_in, const int* in_sizes, int n_in,
                              void* d_out, int out_size, void* d_ws, size_t ws_size,
                              hipStream_t stream) {
    const float* fea    = (const float*)d_in[0];
    const float* weight = (const float*)d_in[1];
    const float* bias   = (const float*)d_in[2];
    float* out = (float*)d_out;

    // ws: Wh | Wl | xb0 | xb1 | flags(8 x 256B)
    const size_t need = (size_t)2 * WELEMS * 2 + (size_t)2 * XBUF_F16 * 2 + 2048;

    copy_row0<<<(N_ * C_ * W_ + 255) / 256, 256, 0, stream>>>(fea, out);

    if (ws_size >= need && d_ws != nullptr) {
        f16* wh  = (f16*)d_ws;
        f16* wl  = wh + WELEMS;
        f16* xb0 = wl + WELEMS;
        f16* xb1 = xb0 + XBUF_F16;
        unsigned* ctr = (unsigned*)(xb1 + XBUF_F16);

        hipMemsetAsync(ctr, 0, 2048, stream);
        prep_w<<<(WELEMS + 255) / 256, 256, 0, stream>>>(weight, wh, wl);
        prep_x0<<<(XT_SZ + 255) / 256, 256, 0, stream>>>(fea, xb0, xb1);

        hipFuncSetAttribute((const void*)conv_persist,
                            hipFuncAttributeMaxDynamicSharedMemorySize, LDS_BYTES);
        conv_persist<<<NBLK, 1024, LDS_BYTES, stream>>>(xb0, xb1, wh, wl, bias, fea, out, ctr);
    } else {
        for (int h = 1; h < H_; h++)
            step_f32<<<256, 256, 0, stream>>>(out, fea, out, weight, bias, h - 1, h);
        for (int h = H_ - 2; h >= 1; h--)
            step_f32<<<256, 256, 0, stream>>>(out, out, out, weight, bias, h + 1, h);
    }
}

// Round 17
// 1337.571 us; speedup vs baseline: 1.2711x; 1.2711x over previous
//
#include <hip/hip_runtime.h>

typedef _Float16 f16;
typedef _Float16 f16x8 __attribute__((ext_vector_type(8)));
typedef _Float16 f16x4 __attribute__((ext_vector_type(4)));
typedef float    f32x4 __attribute__((ext_vector_type(4)));
typedef float    f32x16 __attribute__((ext_vector_type(16)));
typedef unsigned long long u64;

#define N_   8
#define C_   256
#define H_   128
#define W_   128
#define K_   9
#define PAD_ 4
#define WP_  136                    // padded w rows: wp = w + 4, rows 0..135, pads zeroed

#define WELEMS (8*9*16*64*8)        // 589824 = C_*C_*K_ fragment-linear (32x32 layout)
#define XT_SZ  (N_*WP_*256)
#define XBUF_F16 (N_*WP_*512)       // one X buffer: per row 256 hi | 256 lo f16 (pre-swizzled)
#define NBLK   256
#define NSTEP  253
#define RED_OFF  40960
#define WCNT_OFF 73728
#define LDS_BYTES 84992             // >80KB -> 1 block/CU guaranteed

// granule (8 ci = 16B) rotated by 5*wp within 32-granule row (odd mult -> conflict-free b128)
__device__ __host__ inline int xpos(int ci, int wp) {
    int g = ((ci >> 3) + 5 * wp) & 31;
    return g * 8 + (ci & 7);
}

// ---------------- weight prep ----------------
__global__ __launch_bounds__(256) void prep_w(const float* __restrict__ w,
                                              f16* __restrict__ wh, f16* __restrict__ wl) {
    int t = blockIdx.x * 256 + threadIdx.x;
    if (t >= WELEMS) return;
    int j = t & 7;      int q = t >> 3;
    int lane = q & 63;  q >>= 6;
    int c = q & 15;     q >>= 4;
    int k = q % 9;      int ct = q / 9;
    int co = ct * 32 + (lane & 31);
    int ci = c * 16 + (lane >> 5) * 8 + j;
    float wf = w[(co * C_ + ci) * K_ + k];
    f16 hi = (f16)wf;
    f16 lo = (f16)(wf - (float)hi);
    wh[t] = hi;  wl[t] = lo;
}

// ---------------- X init ----------------
__global__ __launch_bounds__(256) void prep_x0(const float* __restrict__ fea,
                                               f16* __restrict__ xb0, f16* __restrict__ xb1) {
    int t = blockIdx.x * 256 + threadIdx.x;
    if (t >= XT_SZ) return;
    int ci = t & 255;
    int wp = (t >> 8) % WP_;
    int n  = t / (WP_ * 256);
    int w  = wp - PAD_;
    bool pad = (unsigned)w >= (unsigned)W_;
    float v = pad ? 0.0f : fea[((size_t)(n * C_ + ci) * H_ + 0) * W_ + w];
    f16 hi = (f16)v;
    f16 lo = (f16)(v - (float)hi);
    size_t row = ((size_t)n * WP_ + wp) * 512;
    int p = xpos(ci, wp);
    xb0[row + p] = hi;  xb0[row + 256 + p] = lo;
    if (pad) { xb1[row + p] = (f16)0.f; xb1[row + 256 + p] = (f16)0.f; }
}

// ---------------- out row0 = fea row0 ----------------
__global__ __launch_bounds__(256) void copy_row0(const float* __restrict__ fea,
                                                 float* __restrict__ out) {
    int idx = blockIdx.x * 256 + threadIdx.x;
    if (idx >= N_ * C_ * W_) return;
    int w = idx % W_;
    int nc = idx / W_;
    size_t off = (size_t)nc * (H_ * W_) + w;
    out[off] = fea[off];
}

// non-rematerializable definition: keeps fragments as asm-defined values
#define TIE(x) asm volatile("" : "+v"(x))

// ---------------- persistent scan kernel (32x32x16 MFMA, resident+streamed weights) ----------------
// 256 blocks x 512 threads = 1 block/CU (LDS-forced). Block b: n=b&7, ct=(b>>3)&7, wq=b>>6.
// Wave wv owns ci-chunk32 wv. VGPR budget is ~128 (compiler targets 2-blk/CU): weights for
// k=0..3 resident (64 VGPR, fits), k=4..8 streamed inline per step (~160KB/CU/step from L2,
// overlapped with MFMA issue). R14 reloaded ALL 288KB/step.
__global__ __launch_bounds__(512, 2)
void conv_persist(
    f16* __restrict__ xb0, f16* __restrict__ xb1,
    const f16* __restrict__ whp, const f16* __restrict__ wlp,
    const float* __restrict__ bias, const float* __restrict__ fea,
    float* out, unsigned* ctr)
{
    extern __shared__ unsigned char Xs[];            // [0,40960) X tile (40 rows x 1024B hi|lo)
    f32x4*    red  = (f32x4*)(Xs + RED_OFF);         // [40960, +32768) partials
    unsigned* wcnt = (unsigned*)(Xs + WCNT_OFF);

    const int b   = blockIdx.x;
    const int n   = b & 7;
    const int ct  = (b >> 3) & 7;
    const int wq  = b >> 6;
    const int w0  = wq * 32;
    const int tid = threadIdx.x;
    const int wv  = tid >> 6;
    const int l   = tid & 63;
    const int m   = l & 31;
    const int hh  = l >> 5;
    unsigned* flags = ctr + n * 64;
    const int bslot = b >> 3;                        // 0..31 within n-group

    if (tid == 0) *wcnt = 0;

    // per-wave weight base: fragment (k, cs) lives at wbase + (k*16 + cs)*512
    const size_t wfb = (((size_t)ct * 9 * 16 + wv * 2) * 64 + l) * 8;
    const f16* whb = whp + wfb;
    const f16* wlb = wlp + wfb;

    // ---- resident weights k=0..3: 4k x 2cs x (hi+lo) = 64 VGPR ----
    f16x8 wkh[4][2], wkl[4][2];
    #pragma unroll
    for (int k = 0; k < 4; ++k)
        #pragma unroll
        for (int cs = 0; cs < 2; ++cs) {
            wkh[k][cs] = *(const f16x8*)&whb[(k * 16 + cs) * 512];
            wkl[k][cs] = *(const f16x8*)&wlb[(k * 16 + cs) * 512];
        }
    #pragma unroll
    for (int k = 0; k < 4; ++k)
        #pragma unroll
        for (int cs = 0; cs < 2; ++cs) { TIE(wkh[k][cs]); TIE(wkl[k][cs]); }
    __syncthreads();   // wcnt init visible

    const int dq = wv & 3;
    const int co_base = ct * 32 + dq * 8 + hh * 4;
    const size_t HW = (size_t)H_ * W_;
    float4 bv = *(const float4*)&bias[co_base];
    const float bvr[4] = {bv.x, bv.y, bv.z, bv.w};

    for (int step = 0; step < NSTEP; ++step) {
        const int  cur   = step & 1;
        const bool fwd   = step < 127;
        const int  h_out = fwd ? (step + 1) : (NSTEP - step);
        const float* radd = fwd ? fea : out;
        const size_t obase = (((size_t)(n * C_ + co_base)) * H_ + h_out) * W_ + w0 + m;
        f16* xcur = cur ? xb1 : xb0;
        f16* xnxt = cur ? xb0 : xb1;

        // ---- stage X tile (40 KB) from IF$: 2xu64 loads -> 1x b128 LDS write per granule ----
        {
            const u64* src = (const u64*)(xcur + ((size_t)n * WP_ + w0) * 512);
            u64 va[5], vb2[5];
            #pragma unroll
            for (int ii = 0; ii < 5; ++ii) {
                int g = tid + ii * 512;
                va[ii]  = __hip_atomic_load(src + (size_t)g * 2,     __ATOMIC_RELAXED, __HIP_MEMORY_SCOPE_AGENT);
                vb2[ii] = __hip_atomic_load(src + (size_t)g * 2 + 1, __ATOMIC_RELAXED, __HIP_MEMORY_SCOPE_AGENT);
            }
            #pragma unroll
            for (int ii = 0; ii < 5; ++ii) {
                int g = tid + ii * 512;
                u64 p[2] = {va[ii], vb2[ii]};
                uint4 qd;
                __builtin_memcpy(&qd, p, 16);
                *(uint4*)(Xs + (size_t)g * 16) = qd;
            }
        }
        // duty waves prefetch radd (latency hides under compute)
        float rv[4] = {0.f, 0.f, 0.f, 0.f};
        if (wv < 4) {
            #pragma unroll
            for (int c2 = 0; c2 < 4; ++c2)
                rv[c2] = radd[obase + (size_t)c2 * HW];
        }
        __syncthreads();                             // S1: X tile ready

        // ---- compute: k=0..3 resident, k=4..8 streamed (load -> 3 MFMA -> dead) ----
        f32x16 a0v{}, crv{};
        #pragma unroll
        for (int k = 0; k < 4; ++k) {
            #pragma unroll
            for (int cs = 0; cs < 2; ++cs) {
                const int rl  = m + k;
                const int gsw = (((wv * 2 + cs) * 2 + hh + 5 * rl) & 31) * 16;
                const unsigned char* base = Xs + rl * 1024 + gsw;
                f16x8 bh = *(const f16x8*)base;
                f16x8 bl = *(const f16x8*)(base + 512);
                a0v = __builtin_amdgcn_mfma_f32_32x32x16_f16(wkh[k][cs], bh, a0v, 0, 0, 0);
                crv = __builtin_amdgcn_mfma_f32_32x32x16_f16(wkh[k][cs], bl, crv, 0, 0, 0);
                crv = __builtin_amdgcn_mfma_f32_32x32x16_f16(wkl[k][cs], bh, crv, 0, 0, 0);
            }
        }
        #pragma unroll
        for (int k = 4; k < 9; ++k) {
            #pragma unroll
            for (int cs = 0; cs < 2; ++cs) {
                f16x8 sh = *(const f16x8*)&whb[(k * 16 + cs) * 512];
                f16x8 sl = *(const f16x8*)&wlb[(k * 16 + cs) * 512];
                const int rl  = m + k;
                const int gsw = (((wv * 2 + cs) * 2 + hh + 5 * rl) & 31) * 16;
                const unsigned char* base = Xs + rl * 1024 + gsw;
                f16x8 bh = *(const f16x8*)base;
                f16x8 bl = *(const f16x8*)(base + 512);
                a0v = __builtin_amdgcn_mfma_f32_32x32x16_f16(sh, bh, a0v, 0, 0, 0);
                crv = __builtin_amdgcn_mfma_f32_32x32x16_f16(sh, bl, crv, 0, 0, 0);
                crv = __builtin_amdgcn_mfma_f32_32x32x16_f16(sl, bh, crv, 0, 0, 0);
            }
        }

        // ---- partials: b128 writes [(chunk*4 + regquad)*64 + l] (conflict-free) ----
        {
            f32x16 sp = a0v + crv;
            #pragma unroll
            for (int rq = 0; rq < 4; ++rq) {
                f32x4 qv = {sp[rq * 4 + 0], sp[rq * 4 + 1], sp[rq * 4 + 2], sp[rq * 4 + 3]};
                red[(wv * 4 + rq) * 64 + l] = qv;
            }
        }
        __syncthreads();                             // S3: red complete

        if (wv < 4) {
            f32x4 s4 = red[(0 * 4 + dq) * 64 + l];
            #pragma unroll
            for (int cc = 1; cc < 8; ++cc)
                s4 += red[(cc * 4 + dq) * 64 + l];
            float y[4];
            #pragma unroll
            for (int c2 = 0; c2 < 4; ++c2)
                y[c2] = fmaxf(s4[c2] + bvr[c2], 0.0f) + rv[c2];

            if (step < NSTEP - 1) {
                // X carry store FIRST (critical path), then drain + mini-bar + flag
                const int wp = w0 + m + PAD_;
                const size_t row = ((size_t)n * WP_ + wp) * 512;
                const int g   = (ct * 4 + dq + 5 * wp) & 31;
                const int pos = g * 8 + hh * 4;
                f16x4 hv, lv;
                #pragma unroll
                for (int c2 = 0; c2 < 4; ++c2) {
                    f16 hi = (f16)y[c2];
                    hv[c2] = hi;
                    lv[c2] = (f16)(y[c2] - (float)hi);
                }
                u64 uh, ul;
                __builtin_memcpy(&uh, &hv, 8);
                __builtin_memcpy(&ul, &lv, 8);
                __hip_atomic_store((u64*)&xnxt[row + pos],       uh, __ATOMIC_RELAXED, __HIP_MEMORY_SCOPE_AGENT);
                __hip_atomic_store((u64*)&xnxt[row + 256 + pos], ul, __ATOMIC_RELAXED, __HIP_MEMORY_SCOPE_AGENT);
                asm volatile("s_waitcnt vmcnt(0)" ::: "memory");   // X stores at IF$
                if (l == 0)
                    __hip_atomic_fetch_add(wcnt, 1u, __ATOMIC_RELAXED, __HIP_MEMORY_SCOPE_WORKGROUP);
                const unsigned tgt = (unsigned)(step + 1);
                if (wv == 0 && l == 0) {
                    while (__hip_atomic_load(wcnt, __ATOMIC_RELAXED, __HIP_MEMORY_SCOPE_WORKGROUP) < 4u * tgt) {}
                    __hip_atomic_store(flags + bslot, tgt, __ATOMIC_RELAXED, __HIP_MEMORY_SCOPE_AGENT);
                }
                // out stores in the poll shadow (same-block consumer only)
                #pragma unroll
                for (int c2 = 0; c2 < 4; ++c2)
                    out[obase + (size_t)c2 * HW] = y[c2];
                if (wv == 0) {
                    while (true) {
                        unsigned v = tgt;
                        if (l < 32)
                            v = __hip_atomic_load(flags + l, __ATOMIC_RELAXED, __HIP_MEMORY_SCOPE_AGENT);
                        if (__all((int)(v >= tgt))) break;
                    }
                }
            } else {
                #pragma unroll
                for (int c2 = 0; c2 < 4; ++c2)
                    out[obase + (size_t)c2 * HW] = y[c2];
            }
        }
        __syncthreads();                             // S4: release (guards Xs reuse)
    }
}

// ---------------- fallback (ws too small): fp32 per-step kernels ----------------
__global__ __launch_bounds__(256) void step_f32(
    const float* __restrict__ xprev, const float* __restrict__ radd,
    float* __restrict__ yout, const float* __restrict__ wsrc,
    const float* __restrict__ bias, int h_prev, int h_out)
{
    __shared__ float XsF[C_][40];
    const int t  = threadIdx.x;
    const int bx = blockIdx.x;
    const int n  = bx & 7;
    const int wb = (bx >> 3) & 3;
    const int cb = bx >> 5;
    const int w0 = wb * 32;
    {
        const size_t nbase = (size_t)n * C_ * (H_ * W_) + (size_t)h_prev * W_;
        for (int idx = t; idx < C_ * 40; idx += 256) {
            int ci = idx / 40;
            int j  = idx - ci * 40;
            int w  = w0 - PAD_ + j;
            float v = 0.0f;
            if ((unsigned)w < (unsigned)W_)
                v = xprev[nbase + (size_t)ci * (H_ * W_) + w];
            XsF[ci][j] = v;
        }
    }
    __syncthreads();
    const int co = cb * 32 + (t >> 3);
    const int w4 = (t & 7) * 4;
    const float* wr = wsrc + (size_t)co * (C_ * K_);
    float acc0 = 0.f, acc1 = 0.f, acc2 = 0.f, acc3 = 0.f;
    for (int ci = 0; ci < C_; ci++) {
        float wk[K_];
        #pragma unroll
        for (int k = 0; k < K_; k++) wk[k] = wr[ci * K_ + k];
        float xv[12];
        float4 a = *(const float4*)&XsF[ci][w4];
        float4 bq = *(const float4*)&XsF[ci][w4 + 4];
        float4 c = *(const float4*)&XsF[ci][w4 + 8];
        xv[0]=a.x; xv[1]=a.y; xv[2]=a.z; xv[3]=a.w;
        xv[4]=bq.x; xv[5]=bq.y; xv[6]=bq.z; xv[7]=bq.w;
        xv[8]=c.x; xv[9]=c.y; xv[10]=c.z; xv[11]=c.w;
        #pragma unroll
        for (int k = 0; k < K_; k++) {
            acc0 = fmaf(wk[k], xv[k],     acc0);
            acc1 = fmaf(wk[k], xv[k + 1], acc1);
            acc2 = fmaf(wk[k], xv[k + 2], acc2);
            acc3 = fmaf(wk[k], xv[k + 3], acc3);
        }
    }
    const float bb = bias[co];
    const size_t obase = (((size_t)n * C_ + co) * H_ + h_out) * W_ + w0 + w4;
    float4 r = *(const float4*)&radd[obase];
    float4 o;
    o.x = fmaxf(acc0 + bb, 0.f) + r.x;
    o.y = fmaxf(acc1 + bb, 0.f) + r.y;
    o.z = fmaxf(acc2 + bb, 0.f) + r.z;
    o.w = fmaxf(acc3 + bb, 0.f) + r.w;
    *(float4*)&yout[obase] = o;
}

extern "C" void kernel_launch(void* const* d_in, const int* in_sizes, int n_in,
                              void* d_out, int out_size, void* d_ws, size_t ws_size,
                              hipStream_t stream) {
    const float* fea    = (const float*)d_in[0];
    const float* weight = (const float*)d_in[1];
    const float* bias   = (const float*)d_in[2];
    float* out = (float*)d_out;

    // ws: Wh | Wl | xb0 | xb1 | flags(8 x 256B)
    const size_t need = (size_t)2 * WELEMS * 2 + (size_t)2 * XBUF_F16 * 2 + 2048;

    copy_row0<<<(N_ * C_ * W_ + 255) / 256, 256, 0, stream>>>(fea, out);

    if (ws_size >= need && d_ws != nullptr) {
        f16* wh  = (f16*)d_ws;
        f16* wl  = wh + WELEMS;
        f16* xb0 = wl + WELEMS;
        f16* xb1 = xb0 + XBUF_F16;
        unsigned* ctr = (unsigned*)(xb1 + XBUF_F16);

        hipMemsetAsync(ctr, 0, 2048, stream);
        prep_w<<<(WELEMS + 255) / 256, 256, 0, stream>>>(weight, wh, wl);
        prep_x0<<<(XT_SZ + 255) / 256, 256, 0, stream>>>(fea, xb0, xb1);

        hipFuncSetAttribute((const void*)conv_persist,
                            hipFuncAttributeMaxDynamicSharedMemorySize, LDS_BYTES);
        conv_persist<<<NBLK, 512, LDS_BYTES, stream>>>(xb0, xb1, wh, wl, bias, fea, out, ctr);
    } else {
        for (int h = 1; h < H_; h++)
            step_f32<<<256, 256, 0, stream>>>(out, fea, out, weight, bias, h - 1, h);
        for (int h = H_ - 2; h >= 1; h--)
            step_f32<<<256, 256, 0, stream>>>(out, out, out, weight, bias, h + 1, h);
    }
}